// Round 3
// baseline (1307.575 us; speedup 1.0000x reference)
//
#include <hip/hip_runtime.h>
#include <hip/hip_bf16.h>

#define BF16 __hip_bfloat16

typedef __bf16 bf16x8 __attribute__((ext_vector_type(8)));
typedef float f32x4 __attribute__((ext_vector_type(4)));

__device__ __forceinline__ void async_copy16(const void* g, void* l) {
    __builtin_amdgcn_global_load_lds(
        (const __attribute__((address_space(1))) void*)g,
        (__attribute__((address_space(3))) void*)l,
        16, 0, 0);
}

// ---------------- fp32 -> bf16 convert with K padding (2D grid, no int div) ----------------
__global__ __launch_bounds__(256) void convert_pad_k(
    const float* __restrict__ src, BF16* __restrict__ dst,
    int Ks, int Kd) {
    const long r = blockIdx.y;
    const int k = (blockIdx.x * 256 + threadIdx.x) * 2;
    if (k >= Kd) return;
    float a = (k < Ks) ? src[r * Ks + k] : 0.f;
    float b = (k + 1 < Ks) ? src[r * Ks + k + 1] : 0.f;
    dst[r * Kd + k] = __float2bfloat16(a);
    dst[r * Kd + k + 1] = __float2bfloat16(b);
}

// ---------------- fused QKV NT GEMM, 256x128 tile, 3-buffer LDS ring ----------------
// Pipeline: prefetch distance = 2 K-tiles; one counted vmcnt + one barrier per K-tile
// (never drains the in-flight prefetch). LDS is XOR-swizzled (granule ^= row&7) with the
// inverse swizzle applied to the global source address (global_load_lds writes linearly).
// X: [N][K] bf16, W packed: [1536][K] = Wq|Wk|Wv. grid (12, 130): bx = m-tile(128), by = n-tile(256).
// 512 threads = 8 waves, each wave owns a 64x64 output sub-tile. K must be a multiple of 64, >=128.
// ALL outputs row-major (V transpose is a separate cheap kernel: scattered 2B stores in the
// epilogue cost ~70k cyc/block and dominated the K=512 layer gemms).
__global__ __launch_bounds__(512, 2) void gemm_qkv(
    const BF16* __restrict__ Xg, const BF16* __restrict__ Wg,
    const float* __restrict__ bqp, const float* __restrict__ bkp, const float* __restrict__ bvp,
    BF16* __restrict__ Qo, BF16* __restrict__ Ko, BF16* __restrict__ Vo,
    int K) {
    __shared__ __align__(16) BF16 As[3][256 * 64];   // 96 KB
    __shared__ __align__(16) BF16 Bs[3][128 * 64];   // 48 KB
    const int tid = threadIdx.x;
    const int w = tid >> 6;
    const int lane = tid & 63;
    const int quad = lane >> 4;
    const int l15 = lane & 15;
    // XCD-aware block swizzle: 1560 blocks, 1560 % 8 == 0 -> simple bijective form.
    const int linear = blockIdx.x + 12 * blockIdx.y;
    const int cpx = (12 * (int)gridDim.y) >> 3;
    const int id2 = (linear & 7) * cpx + (linear >> 3);
    const int bx = id2 % 12;
    const int by = id2 / 12;
    const long n0 = (long)by * 256;
    const long m0full = (long)bx * 128;
    const int sel = bx >> 2;
    const int mbase = (bx & 3) * 128;
    const int wr = (w >> 1) * 64;   // wave's N-row offset (4 groups of 64)
    const int wc = (w & 1) * 64;    // wave's M-col offset (2 groups of 64)
    const int KT = K >> 6;
    // staging: per thread, lane -> (row = lane>>3, 16B-granule = lane&7); inverse-swizzled source col
    const int rl = lane >> 3;
    const int gsw = ((lane & 7) ^ (rl & 7)) * 8;  // element offset of the 16B granule to fetch
    const int rw = w * 8 + rl;

#define STAGE_TILE(k0, buf)                                                              \
    do {                                                                                 \
        _Pragma("unroll")                                                                \
        for (int r_ = 0; r_ < 4; ++r_)                                                   \
            async_copy16(Xg + (n0 + r_ * 64 + rw) * K + (k0) + gsw,                      \
                         &As[buf][(r_ * 64 + w * 8) * 64]);                              \
        _Pragma("unroll")                                                                \
        for (int r_ = 0; r_ < 2; ++r_)                                                   \
            async_copy16(Wg + (m0full + r_ * 64 + rw) * K + (k0) + gsw,                  \
                         &Bs[buf][(r_ * 64 + w * 8) * 64]);                              \
    } while (0)

    f32x4 acc[4][4] = {};
    // prologue: stage K-tiles 0 and 1
    STAGE_TILE(0, 0);
    STAGE_TILE(64, 1);
    int cb = 0;
    for (int kt = 0; kt < KT; ++kt) {
        // counted wait: force this K-tile's 6 loads (issued 2 bodies ago) landed; the
        // newest 6 (next tile's prefetch) stay in flight. Tail body drains fully.
        if (kt + 1 < KT) {
            asm volatile("s_waitcnt vmcnt(6)\n\ts_barrier" ::: "memory");
        } else {
            asm volatile("s_waitcnt vmcnt(0)\n\ts_barrier" ::: "memory");
        }
        __builtin_amdgcn_sched_barrier(0);
        // LDS -> reg fragments (swizzled, bank-conflict-free)
        bf16x8 af[2][4], bfr[2][4];
#pragma unroll
        for (int s = 0; s < 2; ++s) {
#pragma unroll
            for (int i = 0; i < 4; ++i) {
                const int row = wr + i * 16 + l15;
                const int gx = ((s * 4 + quad) ^ (row & 7)) * 8;
                af[s][i] = *(const bf16x8*)&As[cb][row * 64 + gx];
            }
#pragma unroll
            for (int j = 0; j < 4; ++j) {
                const int row = wc + j * 16 + l15;
                const int gx = ((s * 4 + quad) ^ (row & 7)) * 8;
                bfr[s][j] = *(const bf16x8*)&Bs[cb][row * 64 + gx];
            }
        }
        // prefetch K-tile kt+2 into the ring slot freed by kt-1 (safe: every wave past
        // the entry barrier has completed its body(kt-1) LDS reads)
        if (kt + 2 < KT) {
            int nb = cb + 2;
            if (nb >= 3) nb -= 3;
            STAGE_TILE((kt + 2) << 6, nb);
        }
        __builtin_amdgcn_s_setprio(1);
#pragma unroll
        for (int s = 0; s < 2; ++s)
#pragma unroll
            for (int i = 0; i < 4; ++i)
#pragma unroll
                for (int j = 0; j < 4; ++j)
                    acc[i][j] = __builtin_amdgcn_mfma_f32_16x16x32_bf16(af[s][i], bfr[s][j], acc[i][j], 0, 0, 0);
        __builtin_amdgcn_s_setprio(0);
        ++cb;
        if (cb >= 3) cb -= 3;
    }
#undef STAGE_TILE

    const float* bp = (sel == 0) ? bqp : (sel == 1) ? bkp : bvp;
    BF16* out = (sel == 0) ? Qo : (sel == 1) ? Ko : Vo;
#pragma unroll
    for (int j = 0; j < 4; ++j) {
        const int m = mbase + wc + j * 16 + l15;
        const float bz = bp[m];
#pragma unroll
        for (int i = 0; i < 4; ++i) {
#pragma unroll
            for (int r = 0; r < 4; ++r) {
                const long n = n0 + wr + i * 16 + quad * 4 + r;
                float v = acc[i][j][r] + bz;
                if (sel == 2) v = (v >= 0.f) ? v : 0.01f * v;
                out[n * 512 + m] = __float2bfloat16(v);
            }
        }
    }
}

// ---------------- V transpose: Vb[n][512] -> Vt[bb][c][96], zero-padded m in [65,96) ----------------
__global__ __launch_bounds__(256) void vtrans_k(const ushort* __restrict__ Vb,
                                                ushort* __restrict__ Vt) {
    const int bb = blockIdx.x;
    for (int idx = threadIdx.x; idx < 512 * 48; idx += 256) {
        const int c = idx / 48;
        const int m = (idx - c * 48) * 2;
        ushort a = (m < 65) ? Vb[((long)bb * 65 + m) * 512 + c] : (ushort)0;
        ushort b = (m + 1 < 65) ? Vb[((long)bb * 65 + m + 1) * 512 + c] : (ushort)0;
        *(uint*)&Vt[((long)bb * 512 + c) * 96 + m] = (uint)a | ((uint)b << 16);
    }
}

// ---------------- scores + softmax: P[bb][65][96] normalized bf16 ----------------
// Q,K: [33280][512] bf16. One block per bb. 25 S-tiles over 4 waves, STATIC unroll
// (7 slots, slot u live iff w+4u<25) so acc[] / tile coords stay in registers (rule #20).
__global__ __launch_bounds__(256) void attn_scores(
    const BF16* __restrict__ Qg, const BF16* __restrict__ Kg, BF16* __restrict__ Pg) {
    constexpr float SC = 0.04419417382415922f;  // 1/sqrt(512)
    __shared__ __align__(16) BF16 Qs[2][80 * 32];
    __shared__ __align__(16) BF16 Ks[2][80 * 32];
    __shared__ float Sf[80 * 84];
    const int bb = blockIdx.x;
    const int tid = threadIdx.x;
    const int w = tid >> 6, lane = tid & 63, quad = lane >> 4, l15 = lane & 15;
    // compile-time-bounded tile table: slot u -> tile t = w + 4u (guarded by t < 25)
    int i16a[7], j16a[7];
#pragma unroll
    for (int u = 0; u < 7; ++u) {
        const int t = w + 4 * u;
        const int tc = (t < 25) ? t : 0;
        i16a[u] = (tc / 5) * 16;
        j16a[u] = (tc % 5) * 16;
    }
    f32x4 acc[7] = {};
    for (int k0 = 0; k0 < 512; k0 += 64) {
        for (int idx = tid; idx < 1280; idx += 256) {
            const int t = (idx >= 640) ? 1 : 0;
            const int e = idx - t * 640;
            const int sub = (e >= 320) ? 1 : 0;
            const int e2 = e - sub * 320;
            const int row = e2 >> 2;
            const int koff = (e2 & 3) * 8;
            uint4 val = make_uint4(0, 0, 0, 0);
            if (row < 65) {
                const BF16* src = (t ? Kg : Qg) + ((long)(bb * 65 + row) * 512 + k0 + sub * 32 + koff);
                val = *(const uint4*)src;
            }
            *(uint4*)&((t ? Ks : Qs)[sub][row * 32 + koff]) = val;
        }
        __syncthreads();
#pragma unroll
        for (int sub = 0; sub < 2; ++sub) {
#pragma unroll
            for (int u = 0; u < 7; ++u) {
                if (w + 4 * u < 25) {
                    bf16x8 af = *(const bf16x8*)&Qs[sub][(i16a[u] + l15) * 32 + quad * 8];
                    bf16x8 bfr = *(const bf16x8*)&Ks[sub][(j16a[u] + l15) * 32 + quad * 8];
                    acc[u] = __builtin_amdgcn_mfma_f32_16x16x32_bf16(af, bfr, acc[u], 0, 0, 0);
                }
            }
        }
        __syncthreads();
    }
#pragma unroll
    for (int u = 0; u < 7; ++u) {
        if (w + 4 * u < 25) {
#pragma unroll
            for (int r = 0; r < 4; ++r)
                Sf[(i16a[u] + quad * 4 + r) * 84 + j16a[u] + l15] = acc[u][r] * SC;
        }
    }
    __syncthreads();
    // softmax: 4 threads per row
    for (int rr = tid >> 2; rr < 65; rr += 64) {
        const int sub = tid & 3;
        float mx = -1e30f;
        for (int m = sub; m < 65; m += 4) mx = fmaxf(mx, Sf[rr * 84 + m]);
        mx = fmaxf(mx, __shfl_xor(mx, 1));
        mx = fmaxf(mx, __shfl_xor(mx, 2));
        float s = 0.f;
        for (int m = sub; m < 65; m += 4) {
            float e = __expf(Sf[rr * 84 + m] - mx);
            Sf[rr * 84 + m] = e;
            s += e;
        }
        s += __shfl_xor(s, 1);
        s += __shfl_xor(s, 2);
        const float inv = 1.f / s;
        const long base = ((long)bb * 65 + rr) * 96;
        for (int m = sub; m < 96; m += 4) {
            float v = (m < 65) ? Sf[rr * 84 + m] * inv : 0.f;
            Pg[base + m] = __float2bfloat16(v);
        }
    }
}

// ---------------- PV + residual: grid (512, 4) = (bb, 128-c strip) ----------------
// P: [bb][65][96] normalized bf16; Vt: [bb][c][96]; X: [33280][512] in/out.
__global__ __launch_bounds__(256) void attn_pv(
    const BF16* __restrict__ Pg, const BF16* __restrict__ Vt,
    BF16* __restrict__ Xg, int residual) {
    __shared__ __align__(16) BF16 Ps[80 * 104];
    const int bb = blockIdx.x;
    const int c0 = blockIdx.y * 128;
    const int tid = threadIdx.x;
    const int w = tid >> 6, lane = tid & 63, quad = lane >> 4, l15 = lane & 15;
    for (int idx = tid; idx < 960; idx += 256) {
        const int row = idx / 12;
        const int kk = idx - row * 12;
        uint4 val = make_uint4(0, 0, 0, 0);
        if (row < 65) val = *(const uint4*)(Pg + ((long)bb * 65 + row) * 96 + kk * 8);
        *(uint4*)&Ps[row * 104 + kk * 8] = val;
    }
    __syncthreads();
    bf16x8 af[5][3];
#pragma unroll
    for (int i = 0; i < 5; ++i)
#pragma unroll
        for (int ks = 0; ks < 3; ++ks)
            af[i][ks] = *(const bf16x8*)&Ps[(i * 16 + l15) * 104 + ks * 32 + quad * 8];
#pragma unroll
    for (int jj = 0; jj < 2; ++jj) {
        const int c = c0 + (jj * 4 + w) * 16 + l15;
        const BF16* vp = Vt + ((long)bb * 512 + c) * 96 + quad * 8;
        bf16x8 b0 = *(const bf16x8*)vp;
        bf16x8 b1 = *(const bf16x8*)(vp + 32);
        bf16x8 b2 = *(const bf16x8*)(vp + 64);
        f32x4 po[5] = {};
#pragma unroll
        for (int i = 0; i < 5; ++i) {
            po[i] = __builtin_amdgcn_mfma_f32_16x16x32_bf16(af[i][0], b0, po[i], 0, 0, 0);
            po[i] = __builtin_amdgcn_mfma_f32_16x16x32_bf16(af[i][1], b1, po[i], 0, 0, 0);
            po[i] = __builtin_amdgcn_mfma_f32_16x16x32_bf16(af[i][2], b2, po[i], 0, 0, 0);
        }
#pragma unroll
        for (int i = 0; i < 5; ++i)
#pragma unroll
            for (int r = 0; r < 4; ++r) {
                const int l = i * 16 + quad * 4 + r;
                if (l < 65) {
                    const long idx = ((long)(bb * 65 + l)) * 512 + c;
                    float v = po[i][r];
                    if (residual) v += __bfloat162float(Xg[idx]);
                    Xg[idx] = __float2bfloat16(v);
                }
            }
    }
}

// ---------------- mean over L -> Hp[b][s*512+c] fp32 ----------------
__global__ __launch_bounds__(256) void pool_k(const BF16* __restrict__ Xg,
                                              float* __restrict__ Hp) {
    const int sb = blockIdx.x;
    const int s = sb >> 8, b = sb & 255;
    for (int c = threadIdx.x; c < 512; c += 256) {
        float acc = 0.f;
        for (int l = 0; l < 65; ++l)
            acc += __bfloat162float(Xg[((long)sb * 65 + l) * 512 + c]);
        Hp[(long)b * 1024 + s * 512 + c] = acc * (1.f / 65.f);
    }
}

// ---------------- classifier ----------------
__global__ __launch_bounds__(256) void fc_k(
    const float* __restrict__ Hp, const float* __restrict__ W1,
    const float* __restrict__ b1, const float* __restrict__ W2,
    const float* __restrict__ b2, float* __restrict__ out) {
    __shared__ float h[1024];
    __shared__ float h1[256];
    const int b = blockIdx.x, tid = threadIdx.x;
    for (int k = tid; k < 1024; k += 256) h[k] = Hp[(long)b * 1024 + k];
    __syncthreads();
    float acc = b1[tid];
    for (int k = 0; k < 1024; ++k) acc += W1[(long)tid * 1024 + k] * h[k];
    h1[tid] = fmaxf(acc, 0.f);
    __syncthreads();
    const int w = tid >> 6, lane = tid & 63;
    if (w < 2) {
        float p = 0.f;
        for (int u = lane; u < 256; u += 64) p += W2[w * 256 + u] * h1[u];
        for (int off = 32; off > 0; off >>= 1) p += __shfl_down(p, off);
        if (lane == 0) out[b * 2 + w] = p + b2[w];
    }
}

extern "C" void kernel_launch(void* const* d_in, const int* in_sizes, int n_in,
                              void* d_out, int out_size, void* d_ws, size_t ws_size,
                              hipStream_t stream) {
    const float* dataL = (const float*)d_in[0];
    const float* dataR = (const float*)d_in[1];
    const float* Wq0 = (const float*)d_in[2];
    const float* bq0 = (const float*)d_in[3];
    const float* Wk0 = (const float*)d_in[4];
    const float* bk0 = (const float*)d_in[5];
    const float* Wv0 = (const float*)d_in[6];
    const float* bv0 = (const float*)d_in[7];
    const float* Wq = (const float*)d_in[8];
    const float* bq = (const float*)d_in[9];
    const float* Wk = (const float*)d_in[10];
    const float* bk = (const float*)d_in[11];
    const float* Wv = (const float*)d_in[12];
    const float* bv = (const float*)d_in[13];
    const float* W1 = (const float*)d_in[14];
    const float* b1 = (const float*)d_in[15];
    const float* W2 = (const float*)d_in[16];
    const float* b2 = (const float*)d_in[17];

    // ws layout (bytes), total 254,017,536:
    //   Xb @ 0          : 33280 x 2112 bf16 = 140,574,720 (dead after L0 GEMM; region reused:)
    //     X  @ 0        : 34,078,720
    //     Vt @ 34078720 : 512*512*96*2 = 50,331,648  (ends 84,410,368)
    //     Pg @ 84410368 : 512*65*96*2  = 6,389,760   (ends 90,800,128)
    //     Hp @ 90800128 : 256*1024*4   = 1,048,576   (ends 91,848,704)
    //   Wc @ 140574720  : w0 1536x2112 bf16 = 6,488,064 ; wl 9x512x512 bf16 = 4,718,592
    //   Qb @ 151781376  : 34,078,720
    //   Kb @ 185860096  : 34,078,720
    //   Vb @ 219938816  : 34,078,720
    char* ws = (char*)d_ws;
    BF16* Xb = (BF16*)ws;
    BF16* X = Xb;
    BF16* Vt = (BF16*)(ws + 34078720L);
    BF16* Pg = (BF16*)(ws + 84410368L);
    float* Hp = (float*)(ws + 90800128L);
    BF16* Wc = (BF16*)(ws + 140574720L);
    BF16* Qb = (BF16*)(ws + 151781376L);
    BF16* Kb = (BF16*)(ws + 185860096L);
    BF16* Vb = (BF16*)(ws + 219938816L);

    BF16* w0 = Wc;                      // packed [1536][2112]: Wq0|Wk0|Wv0
    BF16* wl = Wc + 3L * 512 * 2112;    // 3 layers, each packed [1536][512]

    auto cvt = [&](const float* src, BF16* dst, long R, int Ks, int Kd) {
        dim3 grid((Kd / 2 + 255) / 256, (unsigned)R);
        convert_pad_k<<<grid, 256, 0, stream>>>(src, dst, Ks, Kd);
    };
    cvt(dataL, Xb, 16640, 2053, 2112);
    cvt(dataR, Xb + 16640L * 2112, 16640, 2053, 2112);
    cvt(Wq0, w0, 512, 2053, 2112);
    cvt(Wk0, w0 + 512L * 2112, 512, 2053, 2112);
    cvt(Wv0, w0 + 2L * 512 * 2112, 512, 2053, 2112);
    for (int n = 0; n < 3; ++n) {
        BF16* base = wl + (long)n * 3 * 262144;
        cvt(Wq + (long)n * 262144, base, 512, 512, 512);
        cvt(Wk + (long)n * 262144, base + 262144, 512, 512, 512);
        cvt(Wv + (long)n * 262144, base + 2 * 262144, 512, 512, 512);
    }

    dim3 ggrid(12, 130);
    dim3 pvgrid(512, 4);
    // layer 0
    gemm_qkv<<<ggrid, 512, 0, stream>>>(Xb, w0, bq0, bk0, bv0, Qb, Kb, Vb, 2112);
    vtrans_k<<<512, 256, 0, stream>>>((const ushort*)Vb, (ushort*)Vt);
    attn_scores<<<512, 256, 0, stream>>>(Qb, Kb, Pg);
    attn_pv<<<pvgrid, 256, 0, stream>>>(Pg, Vt, X, 0);
    // layers 1..3: V row-major into Vb, transposed by vtrans_k (scattered 2B stores in the
    // GEMM epilogue were ~3x the cost of the whole K=512 K-loop)
    for (int n = 0; n < 3; ++n) {
        gemm_qkv<<<ggrid, 512, 0, stream>>>(X, wl + (long)n * 3 * 262144,
                                            bq + n * 512, bk + n * 512, bv + n * 512,
                                            Qb, Kb, Vb, 512);
        vtrans_k<<<512, 256, 0, stream>>>((const ushort*)Vb, (ushort*)Vt);
        attn_scores<<<512, 256, 0, stream>>>(Qb, Kb, Pg);
        attn_pv<<<pvgrid, 256, 0, stream>>>(Pg, Vt, X, 1);
    }
    pool_k<<<512, 256, 0, stream>>>(X, Hp);
    fc_k<<<256, 256, 0, stream>>>(Hp, W1, b1, W2, b2, (float*)d_out);
}

// Round 4
// 1166.022 us; speedup vs baseline: 1.1214x; 1.1214x over previous
//
#include <hip/hip_runtime.h>
#include <hip/hip_bf16.h>

#define BF16 __hip_bfloat16

typedef __bf16 bf16x8 __attribute__((ext_vector_type(8)));
typedef float f32x4 __attribute__((ext_vector_type(4)));

__device__ __forceinline__ void async_copy16(const void* g, void* l) {
    __builtin_amdgcn_global_load_lds(
        (const __attribute__((address_space(1))) void*)g,
        (__attribute__((address_space(3))) void*)l,
        16, 0, 0);
}

// ---------------- fp32 -> bf16 convert with K padding (2D grid, x4 per thread) ----------------
__global__ __launch_bounds__(256) void convert_pad_k(
    const float* __restrict__ src, BF16* __restrict__ dst,
    int Ks, int Kd) {
    const long r = blockIdx.y;
    const int k = (blockIdx.x * 256 + threadIdx.x) * 4;
    if (k >= Kd) return;
    const float* s = src + r * (long)Ks;
    float a0 = (k < Ks) ? s[k] : 0.f;
    float a1 = (k + 1 < Ks) ? s[k + 1] : 0.f;
    float a2 = (k + 2 < Ks) ? s[k + 2] : 0.f;
    float a3 = (k + 3 < Ks) ? s[k + 3] : 0.f;
    BF16 b0 = __float2bfloat16(a0), b1 = __float2bfloat16(a1);
    BF16 b2 = __float2bfloat16(a2), b3 = __float2bfloat16(a3);
    ushort4 o = make_ushort4(*(ushort*)&b0, *(ushort*)&b1, *(ushort*)&b2, *(ushort*)&b3);
    *(ushort4*)&dst[r * (long)Kd + k] = o;
}

// ---------------- fused QKV NT GEMM, 256x128 tile, 3-buffer LDS ring ----------------
// Templated on K so rocprof shows distinct names for L0 (K=2112) vs layers (K=512).
template <int K>
__global__ __launch_bounds__(512, 2) void gemm_qkv(
    const BF16* __restrict__ Xg, const BF16* __restrict__ Wg,
    const float* __restrict__ bqp, const float* __restrict__ bkp, const float* __restrict__ bvp,
    BF16* __restrict__ Qo, BF16* __restrict__ Ko, BF16* __restrict__ Vo) {
    __shared__ __align__(16) BF16 As[3][256 * 64];   // 96 KB
    __shared__ __align__(16) BF16 Bs[3][128 * 64];   // 48 KB
    const int tid = threadIdx.x;
    const int w = tid >> 6;
    const int lane = tid & 63;
    const int quad = lane >> 4;
    const int l15 = lane & 15;
    // XCD-aware block swizzle: 1560 blocks, 1560 % 8 == 0 -> simple bijective form.
    const int linear = blockIdx.x + 12 * blockIdx.y;
    const int cpx = (12 * (int)gridDim.y) >> 3;
    const int id2 = (linear & 7) * cpx + (linear >> 3);
    const int bx = id2 % 12;
    const int by = id2 / 12;
    const long n0 = (long)by * 256;
    const long m0full = (long)bx * 128;
    const int sel = bx >> 2;
    const int mbase = (bx & 3) * 128;
    const int wr = (w >> 1) * 64;   // wave's N-row offset (4 groups of 64)
    const int wc = (w & 1) * 64;    // wave's M-col offset (2 groups of 64)
    constexpr int KT = K >> 6;
    // staging: per thread, lane -> (row = lane>>3, 16B-granule = lane&7); inverse-swizzled source col
    const int rl = lane >> 3;
    const int gsw = ((lane & 7) ^ (rl & 7)) * 8;  // element offset of the 16B granule to fetch
    const int rw = w * 8 + rl;

#define STAGE_TILE(k0, buf)                                                              \
    do {                                                                                 \
        _Pragma("unroll")                                                                \
        for (int r_ = 0; r_ < 4; ++r_)                                                   \
            async_copy16(Xg + (n0 + r_ * 64 + rw) * K + (k0) + gsw,                      \
                         &As[buf][(r_ * 64 + w * 8) * 64]);                              \
        _Pragma("unroll")                                                                \
        for (int r_ = 0; r_ < 2; ++r_)                                                   \
            async_copy16(Wg + (m0full + r_ * 64 + rw) * K + (k0) + gsw,                  \
                         &Bs[buf][(r_ * 64 + w * 8) * 64]);                              \
    } while (0)

    f32x4 acc[4][4] = {};
    // prologue: stage K-tiles 0 and 1
    STAGE_TILE(0, 0);
    STAGE_TILE(64, 1);
    int cb = 0;
    for (int kt = 0; kt < KT; ++kt) {
        // counted wait: force this K-tile's 6 loads (issued 2 bodies ago) landed; the
        // newest 6 (next tile's prefetch) stay in flight. Tail body drains fully.
        if (kt + 1 < KT) {
            asm volatile("s_waitcnt vmcnt(6)\n\ts_barrier" ::: "memory");
        } else {
            asm volatile("s_waitcnt vmcnt(0)\n\ts_barrier" ::: "memory");
        }
        __builtin_amdgcn_sched_barrier(0);
        // LDS -> reg fragments (swizzled, bank-conflict-free)
        bf16x8 af[2][4], bfr[2][4];
#pragma unroll
        for (int s = 0; s < 2; ++s) {
#pragma unroll
            for (int i = 0; i < 4; ++i) {
                const int row = wr + i * 16 + l15;
                const int gx = ((s * 4 + quad) ^ (row & 7)) * 8;
                af[s][i] = *(const bf16x8*)&As[cb][row * 64 + gx];
            }
#pragma unroll
            for (int j = 0; j < 4; ++j) {
                const int row = wc + j * 16 + l15;
                const int gx = ((s * 4 + quad) ^ (row & 7)) * 8;
                bfr[s][j] = *(const bf16x8*)&Bs[cb][row * 64 + gx];
            }
        }
        // prefetch K-tile kt+2 into the ring slot freed by kt-1 (safe: every wave past
        // the entry barrier has completed its body(kt-1) LDS reads)
        if (kt + 2 < KT) {
            int nb = cb + 2;
            if (nb >= 3) nb -= 3;
            STAGE_TILE((kt + 2) << 6, nb);
        }
        __builtin_amdgcn_s_setprio(1);
#pragma unroll
        for (int s = 0; s < 2; ++s)
#pragma unroll
            for (int i = 0; i < 4; ++i)
#pragma unroll
                for (int j = 0; j < 4; ++j)
                    acc[i][j] = __builtin_amdgcn_mfma_f32_16x16x32_bf16(af[s][i], bfr[s][j], acc[i][j], 0, 0, 0);
        __builtin_amdgcn_s_setprio(0);
        ++cb;
        if (cb >= 3) cb -= 3;
    }
#undef STAGE_TILE

    const float* bp = (sel == 0) ? bqp : (sel == 1) ? bkp : bvp;
    BF16* out = (sel == 0) ? Qo : (sel == 1) ? Ko : Vo;
#pragma unroll
    for (int j = 0; j < 4; ++j) {
        const int m = mbase + wc + j * 16 + l15;
        const float bz = bp[m];
#pragma unroll
        for (int i = 0; i < 4; ++i) {
#pragma unroll
            for (int r = 0; r < 4; ++r) {
                const long n = n0 + wr + i * 16 + quad * 4 + r;
                float v = acc[i][j][r] + bz;
                if (sel == 2) v = (v >= 0.f) ? v : 0.01f * v;
                out[n * 512 + m] = __float2bfloat16(v);
            }
        }
    }
}

// ---------------- fused attention: scores + softmax + V-transpose(LDS) + PV + residual --------
// One block per bb (512 blocks, 256 threads). Q,K,V row-major [33280][512] bf16.
// Phase 1: S = QK^T (25 16x16 tiles over 4 waves) -> Sf -> softmax -> P in LDS [80][104] bf16,
//          cols 65..95 and rows 65..79 zeroed.
// Phase 2: per 128-channel chunk: transpose V into LDS Vtl[128][104] (cols m, zero-padded
//          m in [65,96)), then PV MFMAs + residual RMW of X.
__global__ __launch_bounds__(256) void attn_fused(
    const BF16* __restrict__ Qg, const BF16* __restrict__ Kg, const BF16* __restrict__ Vg,
    BF16* __restrict__ Xg, int residual) {
    constexpr float SC = 0.04419417382415922f;  // 1/sqrt(512)
    __shared__ __align__(16) char Us[26624];    // union: QK staging (20480B) | Vtl 128*104*2B
    __shared__ float Sf[80 * 84];               // 26880B
    __shared__ __align__(16) BF16 Pl[80 * 104]; // 16640B
    BF16* qk = (BF16*)Us;                       // buf(t,sub) at qk + (t*2+sub)*2560
    BF16* Vtl = (BF16*)Us;                      // [ch][104], ch local channel
    const int bb = blockIdx.x;
    const int tid = threadIdx.x;
    const int w = tid >> 6, lane = tid & 63, quad = lane >> 4, l15 = lane & 15;

    // ---- Phase 1: scores ----
    int i16a[7], j16a[7];
#pragma unroll
    for (int u = 0; u < 7; ++u) {
        const int t = w + 4 * u;
        const int tc = (t < 25) ? t : 0;
        i16a[u] = (tc / 5) * 16;
        j16a[u] = (tc % 5) * 16;
    }
    f32x4 acc[7] = {};
    for (int k0 = 0; k0 < 512; k0 += 64) {
        for (int idx = tid; idx < 1280; idx += 256) {
            const int t = (idx >= 640) ? 1 : 0;
            const int e = idx - t * 640;
            const int sub = (e >= 320) ? 1 : 0;
            const int e2 = e - sub * 320;
            const int row = e2 >> 2;
            const int koff = (e2 & 3) * 8;
            uint4 val = make_uint4(0, 0, 0, 0);
            if (row < 65) {
                const BF16* src = (t ? Kg : Qg) + ((long)(bb * 65 + row) * 512 + k0 + sub * 32 + koff);
                val = *(const uint4*)src;
            }
            *(uint4*)&qk[(t * 2 + sub) * 2560 + row * 32 + koff] = val;
        }
        __syncthreads();
#pragma unroll
        for (int sub = 0; sub < 2; ++sub) {
#pragma unroll
            for (int u = 0; u < 7; ++u) {
                if (w + 4 * u < 25) {
                    bf16x8 af = *(const bf16x8*)&qk[sub * 2560 + (i16a[u] + l15) * 32 + quad * 8];
                    bf16x8 bfr = *(const bf16x8*)&qk[(2 + sub) * 2560 + (j16a[u] + l15) * 32 + quad * 8];
                    acc[u] = __builtin_amdgcn_mfma_f32_16x16x32_bf16(af, bfr, acc[u], 0, 0, 0);
                }
            }
        }
        __syncthreads();
    }
#pragma unroll
    for (int u = 0; u < 7; ++u) {
        if (w + 4 * u < 25) {
#pragma unroll
            for (int r = 0; r < 4; ++r)
                Sf[(i16a[u] + quad * 4 + r) * 84 + j16a[u] + l15] = acc[u][r] * SC;
        }
    }
    __syncthreads();
    // softmax: 4 threads per row; write normalized bf16 P into Pl
    for (int rr = tid >> 2; rr < 65; rr += 64) {
        const int sub = tid & 3;
        float mx = -1e30f;
        for (int m = sub; m < 65; m += 4) mx = fmaxf(mx, Sf[rr * 84 + m]);
        mx = fmaxf(mx, __shfl_xor(mx, 1));
        mx = fmaxf(mx, __shfl_xor(mx, 2));
        float s = 0.f;
        for (int m = sub; m < 65; m += 4) {
            float e = __expf(Sf[rr * 84 + m] - mx);
            Sf[rr * 84 + m] = e;
            s += e;
        }
        s += __shfl_xor(s, 1);
        s += __shfl_xor(s, 2);
        const float inv = 1.f / s;
        for (int m = sub; m < 96; m += 4) {
            float v = (m < 65) ? Sf[rr * 84 + m] * inv : 0.f;
            Pl[rr * 104 + m] = __float2bfloat16(v);
        }
    }
    // zero P rows 65..79 (cols 0..95) so the PV A-operand is fully defined
    for (int idx = tid; idx < 15 * 48; idx += 256) {
        const int row = 65 + idx / 48;
        const int col = (idx - (idx / 48) * 48) * 2;
        *(uint*)&Pl[row * 104 + col] = 0u;
    }
    // zero Vtl's m in [65,96) for all 128 channels ONCE (chunks only overwrite m < 65,
    // so the zero pad persists across chunks). QK staging region is dead by now.
    for (int idx = tid; idx < 128 * 32; idx += 256) {
        const int m = 65 + (idx & 31);
        if (m < 96) Vtl[(idx >> 5) * 104 + m] = (BF16)0.f;
    }
    __syncthreads();

    // ---- Phase 2: PV over 4 channel chunks ----
    bf16x8 af[5][3];
#pragma unroll
    for (int i = 0; i < 5; ++i)
#pragma unroll
        for (int ks = 0; ks < 3; ++ks)
            af[i][ks] = *(const bf16x8*)&Pl[(i * 16 + l15) * 104 + ks * 32 + quad * 8];

    for (int cc = 0; cc < 4; ++cc) {
        const int c0 = cc * 128;
        // stage V chunk transposed: Vtl[ch][m] = V[m][c0+ch], m < 65
        for (int idx = tid; idx < 65 * 16; idx += 256) {
            const int m = idx >> 4;
            const int cg = idx & 15;
            uint4 val = *(const uint4*)(Vg + ((long)(bb * 65 + m) * 512 + c0 + cg * 8));
            const ushort* u = (const ushort*)&val;
#pragma unroll
            for (int j = 0; j < 8; ++j)
                *(ushort*)&Vtl[(cg * 8 + j) * 104 + m] = u[j];
        }
        __syncthreads();
#pragma unroll
        for (int jj = 0; jj < 2; ++jj) {
            const int ch = (jj * 4 + w) * 16 + l15;
            const int c = c0 + ch;
            bf16x8 b0 = *(const bf16x8*)&Vtl[ch * 104 + quad * 8];
            bf16x8 b1 = *(const bf16x8*)&Vtl[ch * 104 + 32 + quad * 8];
            bf16x8 b2 = *(const bf16x8*)&Vtl[ch * 104 + 64 + quad * 8];
            f32x4 po[5] = {};
#pragma unroll
            for (int i = 0; i < 5; ++i) {
                po[i] = __builtin_amdgcn_mfma_f32_16x16x32_bf16(af[i][0], b0, po[i], 0, 0, 0);
                po[i] = __builtin_amdgcn_mfma_f32_16x16x32_bf16(af[i][1], b1, po[i], 0, 0, 0);
                po[i] = __builtin_amdgcn_mfma_f32_16x16x32_bf16(af[i][2], b2, po[i], 0, 0, 0);
            }
#pragma unroll
            for (int i = 0; i < 5; ++i)
#pragma unroll
                for (int r = 0; r < 4; ++r) {
                    const int l = i * 16 + quad * 4 + r;
                    if (l < 65) {
                        const long idx = ((long)(bb * 65 + l)) * 512 + c;
                        float v = po[i][r];
                        if (residual) v += __bfloat162float(Xg[idx]);
                        Xg[idx] = __float2bfloat16(v);
                    }
                }
        }
        __syncthreads();
    }
}

// ---------------- mean over L -> Hp[b][s*512+c] fp32 ----------------
__global__ __launch_bounds__(256) void pool_k(const BF16* __restrict__ Xg,
                                              float* __restrict__ Hp) {
    const int sb = blockIdx.x;
    const int s = sb >> 8, b = sb & 255;
    for (int c = threadIdx.x; c < 512; c += 256) {
        float acc = 0.f;
        for (int l = 0; l < 65; ++l)
            acc += __bfloat162float(Xg[((long)sb * 65 + l) * 512 + c]);
        Hp[(long)b * 1024 + s * 512 + c] = acc * (1.f / 65.f);
    }
}

// ---------------- classifier ----------------
__global__ __launch_bounds__(256) void fc_k(
    const float* __restrict__ Hp, const float* __restrict__ W1,
    const float* __restrict__ b1, const float* __restrict__ W2,
    const float* __restrict__ b2, float* __restrict__ out) {
    __shared__ float h[1024];
    __shared__ float h1[256];
    const int b = blockIdx.x, tid = threadIdx.x;
    for (int k = tid; k < 1024; k += 256) h[k] = Hp[(long)b * 1024 + k];
    __syncthreads();
    float acc = b1[tid];
    for (int k = 0; k < 1024; ++k) acc += W1[(long)tid * 1024 + k] * h[k];
    h1[tid] = fmaxf(acc, 0.f);
    __syncthreads();
    const int w = tid >> 6, lane = tid & 63;
    if (w < 2) {
        float p = 0.f;
        for (int u = lane; u < 256; u += 64) p += W2[w * 256 + u] * h1[u];
        for (int off = 32; off > 0; off >>= 1) p += __shfl_down(p, off);
        if (lane == 0) out[b * 2 + w] = p + b2[w];
    }
}

extern "C" void kernel_launch(void* const* d_in, const int* in_sizes, int n_in,
                              void* d_out, int out_size, void* d_ws, size_t ws_size,
                              hipStream_t stream) {
    const float* dataL = (const float*)d_in[0];
    const float* dataR = (const float*)d_in[1];
    const float* Wq0 = (const float*)d_in[2];
    const float* bq0 = (const float*)d_in[3];
    const float* Wk0 = (const float*)d_in[4];
    const float* bk0 = (const float*)d_in[5];
    const float* Wv0 = (const float*)d_in[6];
    const float* bv0 = (const float*)d_in[7];
    const float* Wq = (const float*)d_in[8];
    const float* bq = (const float*)d_in[9];
    const float* Wk = (const float*)d_in[10];
    const float* bk = (const float*)d_in[11];
    const float* Wv = (const float*)d_in[12];
    const float* bv = (const float*)d_in[13];
    const float* W1 = (const float*)d_in[14];
    const float* b1 = (const float*)d_in[15];
    const float* W2 = (const float*)d_in[16];
    const float* b2 = (const float*)d_in[17];

    // ws layout (bytes), total 254,017,536:
    //   Xb @ 0          : 33280 x 2112 bf16 = 140,574,720 (dead after L0 GEMM; region reused:)
    //     X  @ 0        : 34,078,720
    //     Hp @ 90800128 : 256*1024*4   = 1,048,576
    //   Wc @ 140574720  : w0 1536x2112 bf16 = 6,488,064 ; wl 9x512x512 bf16 = 4,718,592
    //   Qb @ 151781376  : 34,078,720
    //   Kb @ 185860096  : 34,078,720
    //   Vb @ 219938816  : 34,078,720
    char* ws = (char*)d_ws;
    BF16* Xb = (BF16*)ws;
    BF16* X = Xb;
    float* Hp = (float*)(ws + 90800128L);
    BF16* Wc = (BF16*)(ws + 140574720L);
    BF16* Qb = (BF16*)(ws + 151781376L);
    BF16* Kb = (BF16*)(ws + 185860096L);
    BF16* Vb = (BF16*)(ws + 219938816L);

    BF16* w0 = Wc;                      // packed [1536][2112]: Wq0|Wk0|Wv0
    BF16* wl = Wc + 3L * 512 * 2112;    // 3 layers, each packed [1536][512]

    auto cvt = [&](const float* src, BF16* dst, long R, int Ks, int Kd) {
        dim3 grid((Kd / 4 + 255) / 256, (unsigned)R);
        convert_pad_k<<<grid, 256, 0, stream>>>(src, dst, Ks, Kd);
    };
    cvt(dataL, Xb, 16640, 2053, 2112);
    cvt(dataR, Xb + 16640L * 2112, 16640, 2053, 2112);
    cvt(Wq0, w0, 512, 2053, 2112);
    cvt(Wk0, w0 + 512L * 2112, 512, 2053, 2112);
    cvt(Wv0, w0 + 2L * 512 * 2112, 512, 2053, 2112);
    for (int n = 0; n < 3; ++n) {
        BF16* base = wl + (long)n * 3 * 262144;
        cvt(Wq + (long)n * 262144, base, 512, 512, 512);
        cvt(Wk + (long)n * 262144, base + 262144, 512, 512, 512);
        cvt(Wv + (long)n * 262144, base + 2 * 262144, 512, 512, 512);
    }

    dim3 ggrid(12, 130);
    // layer 0
    gemm_qkv<2112><<<ggrid, 512, 0, stream>>>(Xb, w0, bq0, bk0, bv0, Qb, Kb, Vb);
    attn_fused<<<512, 256, 0, stream>>>(Qb, Kb, Vb, X, 0);
    // layers 1..3
    for (int n = 0; n < 3; ++n) {
        gemm_qkv<512><<<ggrid, 512, 0, stream>>>(X, wl + (long)n * 3 * 262144,
                                                 bq + n * 512, bk + n * 512, bv + n * 512,
                                                 Qb, Kb, Vb);
        attn_fused<<<512, 256, 0, stream>>>(Qb, Kb, Vb, X, 1);
    }
    pool_k<<<512, 256, 0, stream>>>(X, Hp);
    fc_k<<<256, 256, 0, stream>>>(Hp, W1, b1, W2, b2, (float*)d_out);
}

// Round 5
// 1165.985 us; speedup vs baseline: 1.1214x; 1.0000x over previous
//
#include <hip/hip_runtime.h>
#include <hip/hip_bf16.h>

#define BF16 __hip_bfloat16

typedef __bf16 bf16x8 __attribute__((ext_vector_type(8)));
typedef float f32x4 __attribute__((ext_vector_type(4)));

__device__ __forceinline__ void async_copy16(const void* g, void* l) {
    __builtin_amdgcn_global_load_lds(
        (const __attribute__((address_space(1))) void*)g,
        (__attribute__((address_space(3))) void*)l,
        16, 0, 0);
}

// ---------------- fp32 -> bf16 convert with K padding (2D grid, x4 per thread) ----------------
__global__ __launch_bounds__(256) void convert_pad_k(
    const float* __restrict__ src, BF16* __restrict__ dst,
    int Ks, int Kd) {
    const long r = blockIdx.y;
    const int k = (blockIdx.x * 256 + threadIdx.x) * 4;
    if (k >= Kd) return;
    const float* s = src + r * (long)Ks;
    float a0 = (k < Ks) ? s[k] : 0.f;
    float a1 = (k + 1 < Ks) ? s[k + 1] : 0.f;
    float a2 = (k + 2 < Ks) ? s[k + 2] : 0.f;
    float a3 = (k + 3 < Ks) ? s[k + 3] : 0.f;
    BF16 b0 = __float2bfloat16(a0), b1 = __float2bfloat16(a1);
    BF16 b2 = __float2bfloat16(a2), b3 = __float2bfloat16(a3);
    ushort4 o = make_ushort4(*(ushort*)&b0, *(ushort*)&b1, *(ushort*)&b2, *(ushort*)&b3);
    *(ushort4*)&dst[r * (long)Kd + k] = o;
}

// ---------------- fused QKV NT GEMM, 256x128 tile, BK=32, 3-buffer LDS ring (72 KB) ----------------
// 72 KB LDS -> 2 blocks/CU (was 144 KB -> 1 block/CU): barrier drains now overlap across blocks.
// Prefetch distance = 2 K-tiles; counted vmcnt(3) per body (1 tile in flight x 3 loads).
// Swizzle: LDS granule slot = quad ^ ((row>>1)&3); staging pre-applies the same involution on the
// global source column (lane-only constant since rows step by 4 per lane group).
template <int K>
__device__ __forceinline__ void gemm_body(
    const BF16* __restrict__ Xg, const BF16* __restrict__ Wg,
    const float* __restrict__ bqp, const float* __restrict__ bkp, const float* __restrict__ bvp,
    BF16* __restrict__ Qo, BF16* __restrict__ Ko, BF16* __restrict__ Vo) {
    __shared__ __align__(16) BF16 As[3][256 * 32];   // 48 KB
    __shared__ __align__(16) BF16 Bs[3][128 * 32];   // 24 KB
    const int tid = threadIdx.x;
    const int w = tid >> 6;
    const int lane = tid & 63;
    const int quad = lane >> 4;
    const int l15 = lane & 15;
    // XCD-aware block swizzle: 1560 blocks, 1560 % 8 == 0 -> simple bijective form.
    const int linear = blockIdx.x + 12 * blockIdx.y;
    const int cpx = (12 * (int)gridDim.y) >> 3;
    const int id2 = (linear & 7) * cpx + (linear >> 3);
    const int bx = id2 % 12;
    const int by = id2 / 12;
    const long n0 = (long)by * 256;
    const long m0full = (long)bx * 128;
    const int sel = bx >> 2;
    const int mbase = (bx & 3) * 128;
    const int wr = (w >> 1) * 64;   // wave's N-row offset (4 groups of 64)
    const int wc = (w & 1) * 64;    // wave's M-col offset (2 groups of 64)
    constexpr int KT = K >> 5;
    // staging: thread -> (row = w*16 + lane>>2, granule slot = lane&3);
    // source granule = slot ^ f(row), f(row) = (row>>1)&3 -> lane-only: (lane>>3)&3
    const int rw = w * 16 + (lane >> 2);
    const int gsw = ((lane & 3) ^ ((lane >> 3) & 3)) * 8;  // element offset of source granule
    // read-side: slot holding logical granule `quad` of row: quad ^ ((row>>1)&3), rows stepped
    // by l15 with 16-aligned bases -> lane-only constant
    const int gx = (quad ^ ((l15 >> 1) & 3)) * 8;

#define STAGE_TILE(k0, buf)                                                              \
    do {                                                                                 \
        _Pragma("unroll")                                                                \
        for (int r_ = 0; r_ < 2; ++r_)                                                   \
            async_copy16(Xg + (n0 + r_ * 128 + rw) * K + (k0) + gsw,                     \
                         &As[buf][(r_ * 128 + w * 16) * 32]);                            \
        async_copy16(Wg + (m0full + rw) * K + (k0) + gsw,                                \
                     &Bs[buf][(w * 16) * 32]);                                           \
    } while (0)

    f32x4 acc[4][4] = {};
    // prologue: stage K-tiles 0 and 1
    STAGE_TILE(0, 0);
    STAGE_TILE(32, 1);
    int cb = 0;
    for (int kt = 0; kt < KT; ++kt) {
        // counted wait: tile kt's 3 loads landed; tile kt+1's 3 stay in flight.
        if (kt + 1 < KT) {
            asm volatile("s_waitcnt vmcnt(3)\n\ts_barrier" ::: "memory");
        } else {
            asm volatile("s_waitcnt vmcnt(0)\n\ts_barrier" ::: "memory");
        }
        __builtin_amdgcn_sched_barrier(0);
        // LDS -> reg fragments (swizzled, conflict-free)
        bf16x8 af[4], bfr[4];
#pragma unroll
        for (int i = 0; i < 4; ++i)
            af[i] = *(const bf16x8*)&As[cb][(wr + i * 16 + l15) * 32 + gx];
#pragma unroll
        for (int j = 0; j < 4; ++j)
            bfr[j] = *(const bf16x8*)&Bs[cb][(wc + j * 16 + l15) * 32 + gx];
        // prefetch K-tile kt+2 into the ring slot freed by kt-1
        if (kt + 2 < KT) {
            int nb = cb + 2;
            if (nb >= 3) nb -= 3;
            STAGE_TILE((kt + 2) << 5, nb);
        }
        __builtin_amdgcn_s_setprio(1);
#pragma unroll
        for (int i = 0; i < 4; ++i)
#pragma unroll
            for (int j = 0; j < 4; ++j)
                acc[i][j] = __builtin_amdgcn_mfma_f32_16x16x32_bf16(af[i], bfr[j], acc[i][j], 0, 0, 0);
        __builtin_amdgcn_s_setprio(0);
        ++cb;
        if (cb >= 3) cb -= 3;
    }
#undef STAGE_TILE

    const float* bp = (sel == 0) ? bqp : (sel == 1) ? bkp : bvp;
    BF16* out = (sel == 0) ? Qo : (sel == 1) ? Ko : Vo;
#pragma unroll
    for (int j = 0; j < 4; ++j) {
        const int m = mbase + wc + j * 16 + l15;
        const float bz = bp[m];
#pragma unroll
        for (int i = 0; i < 4; ++i) {
#pragma unroll
            for (int r = 0; r < 4; ++r) {
                const long n = n0 + wr + i * 16 + quad * 4 + r;
                float v = acc[i][j][r] + bz;
                if (sel == 2) v = (v >= 0.f) ? v : 0.01f * v;
                out[n * 512 + m] = __float2bfloat16(v);
            }
        }
    }
}

__global__ __launch_bounds__(512, 2) void gemm_k2112(
    const BF16* __restrict__ Xg, const BF16* __restrict__ Wg,
    const float* __restrict__ bqp, const float* __restrict__ bkp, const float* __restrict__ bvp,
    BF16* __restrict__ Qo, BF16* __restrict__ Ko, BF16* __restrict__ Vo) {
    gemm_body<2112>(Xg, Wg, bqp, bkp, bvp, Qo, Ko, Vo);
}

__global__ __launch_bounds__(512, 2) void gemm_k512(
    const BF16* __restrict__ Xg, const BF16* __restrict__ Wg,
    const float* __restrict__ bqp, const float* __restrict__ bkp, const float* __restrict__ bvp,
    BF16* __restrict__ Qo, BF16* __restrict__ Ko, BF16* __restrict__ Vo) {
    gemm_body<512>(Xg, Wg, bqp, bkp, bvp, Qo, Ko, Vo);
}

// ---------------- fused attention: scores + softmax + V-transpose(LDS) + PV + residual --------
// One block per bb (512 blocks, 256 threads). Q,K,V row-major [33280][512] bf16.
__global__ __launch_bounds__(256) void attn_fused(
    const BF16* __restrict__ Qg, const BF16* __restrict__ Kg, const BF16* __restrict__ Vg,
    BF16* __restrict__ Xg, int residual) {
    constexpr float SC = 0.04419417382415922f;  // 1/sqrt(512)
    __shared__ __align__(16) char Us[26624];    // union: QK staging (20480B) | Vtl 128*104*2B
    __shared__ float Sf[80 * 84];               // 26880B
    __shared__ __align__(16) BF16 Pl[80 * 104]; // 16640B
    BF16* qk = (BF16*)Us;                       // buf(t,sub) at qk + (t*2+sub)*2560
    BF16* Vtl = (BF16*)Us;                      // [ch][104], ch local channel
    const int bb = blockIdx.x;
    const int tid = threadIdx.x;
    const int w = tid >> 6, lane = tid & 63, quad = lane >> 4, l15 = lane & 15;

    // ---- Phase 1: scores ----
    int i16a[7], j16a[7];
#pragma unroll
    for (int u = 0; u < 7; ++u) {
        const int t = w + 4 * u;
        const int tc = (t < 25) ? t : 0;
        i16a[u] = (tc / 5) * 16;
        j16a[u] = (tc % 5) * 16;
    }
    f32x4 acc[7] = {};
    for (int k0 = 0; k0 < 512; k0 += 64) {
        for (int idx = tid; idx < 1280; idx += 256) {
            const int t = (idx >= 640) ? 1 : 0;
            const int e = idx - t * 640;
            const int sub = (e >= 320) ? 1 : 0;
            const int e2 = e - sub * 320;
            const int row = e2 >> 2;
            const int koff = (e2 & 3) * 8;
            uint4 val = make_uint4(0, 0, 0, 0);
            if (row < 65) {
                const BF16* src = (t ? Kg : Qg) + ((long)(bb * 65 + row) * 512 + k0 + sub * 32 + koff);
                val = *(const uint4*)src;
            }
            *(uint4*)&qk[(t * 2 + sub) * 2560 + row * 32 + koff] = val;
        }
        __syncthreads();
#pragma unroll
        for (int sub = 0; sub < 2; ++sub) {
#pragma unroll
            for (int u = 0; u < 7; ++u) {
                if (w + 4 * u < 25) {
                    bf16x8 af = *(const bf16x8*)&qk[sub * 2560 + (i16a[u] + l15) * 32 + quad * 8];
                    bf16x8 bfr = *(const bf16x8*)&qk[(2 + sub) * 2560 + (j16a[u] + l15) * 32 + quad * 8];
                    acc[u] = __builtin_amdgcn_mfma_f32_16x16x32_bf16(af, bfr, acc[u], 0, 0, 0);
                }
            }
        }
        __syncthreads();
    }
#pragma unroll
    for (int u = 0; u < 7; ++u) {
        if (w + 4 * u < 25) {
#pragma unroll
            for (int r = 0; r < 4; ++r)
                Sf[(i16a[u] + quad * 4 + r) * 84 + j16a[u] + l15] = acc[u][r] * SC;
        }
    }
    __syncthreads();
    // softmax: 4 threads per row; write normalized bf16 P into Pl
    for (int rr = tid >> 2; rr < 65; rr += 64) {
        const int sub = tid & 3;
        float mx = -1e30f;
        for (int m = sub; m < 65; m += 4) mx = fmaxf(mx, Sf[rr * 84 + m]);
        mx = fmaxf(mx, __shfl_xor(mx, 1));
        mx = fmaxf(mx, __shfl_xor(mx, 2));
        float s = 0.f;
        for (int m = sub; m < 65; m += 4) {
            float e = __expf(Sf[rr * 84 + m] - mx);
            Sf[rr * 84 + m] = e;
            s += e;
        }
        s += __shfl_xor(s, 1);
        s += __shfl_xor(s, 2);
        const float inv = 1.f / s;
        for (int m = sub; m < 96; m += 4) {
            float v = (m < 65) ? Sf[rr * 84 + m] * inv : 0.f;
            Pl[rr * 104 + m] = __float2bfloat16(v);
        }
    }
    // zero P rows 65..79 (cols 0..95) so the PV A-operand is fully defined
    for (int idx = tid; idx < 15 * 48; idx += 256) {
        const int row = 65 + idx / 48;
        const int col = (idx - (idx / 48) * 48) * 2;
        *(uint*)&Pl[row * 104 + col] = 0u;
    }
    // zero Vtl's m in [65,96) for all 128 channels ONCE (chunks only overwrite m < 65,
    // so the zero pad persists across chunks). QK staging region is dead by now.
    for (int idx = tid; idx < 128 * 32; idx += 256) {
        const int m = 65 + (idx & 31);
        if (m < 96) Vtl[(idx >> 5) * 104 + m] = (BF16)0.f;
    }
    __syncthreads();

    // ---- Phase 2: PV over 4 channel chunks ----
    bf16x8 af[5][3];
#pragma unroll
    for (int i = 0; i < 5; ++i)
#pragma unroll
        for (int ks = 0; ks < 3; ++ks)
            af[i][ks] = *(const bf16x8*)&Pl[(i * 16 + l15) * 104 + ks * 32 + quad * 8];

    for (int cc = 0; cc < 4; ++cc) {
        const int c0 = cc * 128;
        // stage V chunk transposed: Vtl[ch][m] = V[m][c0+ch], m < 65
        for (int idx = tid; idx < 65 * 16; idx += 256) {
            const int m = idx >> 4;
            const int cg = idx & 15;
            uint4 val = *(const uint4*)(Vg + ((long)(bb * 65 + m) * 512 + c0 + cg * 8));
            const ushort* u = (const ushort*)&val;
#pragma unroll
            for (int j = 0; j < 8; ++j)
                *(ushort*)&Vtl[(cg * 8 + j) * 104 + m] = u[j];
        }
        __syncthreads();
#pragma unroll
        for (int jj = 0; jj < 2; ++jj) {
            const int ch = (jj * 4 + w) * 16 + l15;
            const int c = c0 + ch;
            bf16x8 b0 = *(const bf16x8*)&Vtl[ch * 104 + quad * 8];
            bf16x8 b1 = *(const bf16x8*)&Vtl[ch * 104 + 32 + quad * 8];
            bf16x8 b2 = *(const bf16x8*)&Vtl[ch * 104 + 64 + quad * 8];
            f32x4 po[5] = {};
#pragma unroll
            for (int i = 0; i < 5; ++i) {
                po[i] = __builtin_amdgcn_mfma_f32_16x16x32_bf16(af[i][0], b0, po[i], 0, 0, 0);
                po[i] = __builtin_amdgcn_mfma_f32_16x16x32_bf16(af[i][1], b1, po[i], 0, 0, 0);
                po[i] = __builtin_amdgcn_mfma_f32_16x16x32_bf16(af[i][2], b2, po[i], 0, 0, 0);
            }
#pragma unroll
            for (int i = 0; i < 5; ++i)
#pragma unroll
                for (int r = 0; r < 4; ++r) {
                    const int l = i * 16 + quad * 4 + r;
                    if (l < 65) {
                        const long idx = ((long)(bb * 65 + l)) * 512 + c;
                        float v = po[i][r];
                        if (residual) v += __bfloat162float(Xg[idx]);
                        Xg[idx] = __float2bfloat16(v);
                    }
                }
        }
        __syncthreads();
    }
}

// ---------------- mean over L -> Hp[b][s*512+c] fp32 ----------------
__global__ __launch_bounds__(256) void pool_k(const BF16* __restrict__ Xg,
                                              float* __restrict__ Hp) {
    const int sb = blockIdx.x;
    const int s = sb >> 8, b = sb & 255;
    for (int c = threadIdx.x; c < 512; c += 256) {
        float acc = 0.f;
        for (int l = 0; l < 65; ++l)
            acc += __bfloat162float(Xg[((long)sb * 65 + l) * 512 + c]);
        Hp[(long)b * 1024 + s * 512 + c] = acc * (1.f / 65.f);
    }
}

// ---------------- classifier ----------------
__global__ __launch_bounds__(256) void fc_k(
    const float* __restrict__ Hp, const float* __restrict__ W1,
    const float* __restrict__ b1, const float* __restrict__ W2,
    const float* __restrict__ b2, float* __restrict__ out) {
    __shared__ float h[1024];
    __shared__ float h1[256];
    const int b = blockIdx.x, tid = threadIdx.x;
    for (int k = tid; k < 1024; k += 256) h[k] = Hp[(long)b * 1024 + k];
    __syncthreads();
    float acc = b1[tid];
    for (int k = 0; k < 1024; ++k) acc += W1[(long)tid * 1024 + k] * h[k];
    h1[tid] = fmaxf(acc, 0.f);
    __syncthreads();
    const int w = tid >> 6, lane = tid & 63;
    if (w < 2) {
        float p = 0.f;
        for (int u = lane; u < 256; u += 64) p += W2[w * 256 + u] * h1[u];
        for (int off = 32; off > 0; off >>= 1) p += __shfl_down(p, off);
        if (lane == 0) out[b * 2 + w] = p + b2[w];
    }
}

extern "C" void kernel_launch(void* const* d_in, const int* in_sizes, int n_in,
                              void* d_out, int out_size, void* d_ws, size_t ws_size,
                              hipStream_t stream) {
    const float* dataL = (const float*)d_in[0];
    const float* dataR = (const float*)d_in[1];
    const float* Wq0 = (const float*)d_in[2];
    const float* bq0 = (const float*)d_in[3];
    const float* Wk0 = (const float*)d_in[4];
    const float* bk0 = (const float*)d_in[5];
    const float* Wv0 = (const float*)d_in[6];
    const float* bv0 = (const float*)d_in[7];
    const float* Wq = (const float*)d_in[8];
    const float* bq = (const float*)d_in[9];
    const float* Wk = (const float*)d_in[10];
    const float* bk = (const float*)d_in[11];
    const float* Wv = (const float*)d_in[12];
    const float* bv = (const float*)d_in[13];
    const float* W1 = (const float*)d_in[14];
    const float* b1 = (const float*)d_in[15];
    const float* W2 = (const float*)d_in[16];
    const float* b2 = (const float*)d_in[17];

    // ws layout (bytes), total 254,017,536:
    //   Xb @ 0          : 33280 x 2112 bf16 = 140,574,720 (dead after L0 GEMM; region reused:)
    //     X  @ 0        : 34,078,720
    //     Hp @ 90800128 : 256*1024*4   = 1,048,576
    //   Wc @ 140574720  : w0 1536x2112 bf16 = 6,488,064 ; wl 9x512x512 bf16 = 4,718,592
    //   Qb @ 151781376  : 34,078,720
    //   Kb @ 185860096  : 34,078,720
    //   Vb @ 219938816  : 34,078,720
    char* ws = (char*)d_ws;
    BF16* Xb = (BF16*)ws;
    BF16* X = Xb;
    float* Hp = (float*)(ws + 90800128L);
    BF16* Wc = (BF16*)(ws + 140574720L);
    BF16* Qb = (BF16*)(ws + 151781376L);
    BF16* Kb = (BF16*)(ws + 185860096L);
    BF16* Vb = (BF16*)(ws + 219938816L);

    BF16* w0 = Wc;                      // packed [1536][2112]: Wq0|Wk0|Wv0
    BF16* wl = Wc + 3L * 512 * 2112;    // 3 layers, each packed [1536][512]

    auto cvt = [&](const float* src, BF16* dst, long R, int Ks, int Kd) {
        dim3 grid((Kd / 4 + 255) / 256, (unsigned)R);
        convert_pad_k<<<grid, 256, 0, stream>>>(src, dst, Ks, Kd);
    };
    cvt(dataL, Xb, 16640, 2053, 2112);
    cvt(dataR, Xb + 16640L * 2112, 16640, 2053, 2112);
    cvt(Wq0, w0, 512, 2053, 2112);
    cvt(Wk0, w0 + 512L * 2112, 512, 2053, 2112);
    cvt(Wv0, w0 + 2L * 512 * 2112, 512, 2053, 2112);
    for (int n = 0; n < 3; ++n) {
        BF16* base = wl + (long)n * 3 * 262144;
        cvt(Wq + (long)n * 262144, base, 512, 512, 512);
        cvt(Wk + (long)n * 262144, base + 262144, 512, 512, 512);
        cvt(Wv + (long)n * 262144, base + 2 * 262144, 512, 512, 512);
    }

    dim3 ggrid(12, 130);
    // layer 0
    gemm_k2112<<<ggrid, 512, 0, stream>>>(Xb, w0, bq0, bk0, bv0, Qb, Kb, Vb);
    attn_fused<<<512, 256, 0, stream>>>(Qb, Kb, Vb, X, 0);
    // layers 1..3
    for (int n = 0; n < 3; ++n) {
        gemm_k512<<<ggrid, 512, 0, stream>>>(X, wl + (long)n * 3 * 262144,
                                             bq + n * 512, bk + n * 512, bv + n * 512,
                                             Qb, Kb, Vb);
        attn_fused<<<512, 256, 0, stream>>>(Qb, Kb, Vb, X, 1);
    }
    pool_k<<<512, 256, 0, stream>>>(X, Hp);
    fc_k<<<256, 256, 0, stream>>>(Hp, W1, b1, W2, b2, (float*)d_out);
}